// Round 1
// baseline (1225.621 us; speedup 1.0000x reference)
//
#include <hip/hip_runtime.h>
#include <hip/hip_bf16.h>
#include <math.h>

#define NPG   256
#define EPG   4096
#define NGRAPH 1024
#define NATTR 100000
#define HID   32
#define DLAT  97

// 101.7 MB scratch for the per-node 97-dim feature rows (avoids relying on ws_size)
__device__ float g_feat[(size_t)NGRAPH * NPG * DLAT];

// ---------------- Kernel A LDS layout (bytes) ----------------
#define A_SSRC   0        // ushort[4096]  8192
#define A_SEW    8192     // float[4096]  16384
#define A_ROWS   24576    // int[257]      1028 (pad 1056)
#define A_NS     25632    // float[256]
#define A_ND     26656    // float[256]
#define A_NID    27680    // int[256]
#define A_FID    28704    // int[256]
#define A_R      29728    // union region
// phase E (within R)
#define A_RAWSD  0        // uint[4096]
#define A_EWRAW  16384    // float[4096]
#define A_DEGIN  32768    // int[256]
#define A_DEGOUT 33792    // int[256]
#define A_CURSOR 34816    // int[256]
// phase L (within R)
#define A_HS     0        // float[256*36]   36864
#define A_AGG    36864    // float[256*36]   36864
#define A_Z      73728    // float[256*32]   32768
#define A_WT     106496   // float[1024]      4096
#define A_RSIZE  110592
#define A_TOTAL  (A_R + A_RSIZE)   // 140320 bytes < 160 KiB

__device__ __forceinline__ void aggregate_edges(const ushort* sSrc, const float* sEw,
                                                const int* rowS, const float* HS,
                                                float* AGG, const float* nd, int t)
{
    const int wv   = t >> 6;
    const int lane = t & 63;
    const int q    = lane & 7;   // dim quad 0..7
    const int p    = lane >> 3;  // edge slot 0..7
    for (int n = wv; n < NPG; n += 8) {
        const int rs = rowS[n], re = rowS[n + 1];
        double a0 = 0.0, a1 = 0.0, a2 = 0.0, a3 = 0.0;
        for (int e = rs + p; e < re; e += 8) {
            const int s = sSrc[e];
            const double wgt = (double)sEw[e];
            const float4 h4 = *(const float4*)(HS + s * 36 + q * 4);
            a0 += (double)h4.x * wgt;
            a1 += (double)h4.y * wgt;
            a2 += (double)h4.z * wgt;
            a3 += (double)h4.w * wgt;
        }
        #pragma unroll
        for (int off = 8; off <= 32; off <<= 1) {
            a0 += __shfl_xor(a0, off, 64);
            a1 += __shfl_xor(a1, off, 64);
            a2 += __shfl_xor(a2, off, 64);
            a3 += __shfl_xor(a3, off, 64);
        }
        if (p == 0) {
            const float sc = nd[n];
            float4 o;
            o.x = (float)a0 * sc; o.y = (float)a1 * sc;
            o.z = (float)a2 * sc; o.w = (float)a3 * sc;
            *(float4*)(AGG + n * 36 + q * 4) = o;
        }
    }
}

extern "C" __global__ void __launch_bounds__(512, 1)
gnn_layers(const int* __restrict__ feats, const int* __restrict__ node_id,
           const int* __restrict__ edge_id, const int* __restrict__ src,
           const int* __restrict__ dst,
           const float* __restrict__ ndata, const float* __restrict__ edata,
           const float* __restrict__ node_emb,
           const float* __restrict__ W0, const float* __restrict__ b0,
           const float* __restrict__ W1, const float* __restrict__ b1,
           const float* __restrict__ W2, const float* __restrict__ b2,
           const float* __restrict__ W3, const float* __restrict__ b3)
{
    extern __shared__ char smem[];
    ushort* sSrc  = (ushort*)(smem + A_SSRC);
    float*  sEw   = (float*)(smem + A_SEW);
    int*    rowS  = (int*)(smem + A_ROWS);
    float*  ns    = (float*)(smem + A_NS);
    float*  nd    = (float*)(smem + A_ND);
    int*    nid   = (int*)(smem + A_NID);
    int*    fid   = (int*)(smem + A_FID);
    char*   R     = smem + A_R;
    uint*   rawSD = (uint*)(R + A_RAWSD);
    float*  ewRaw = (float*)(R + A_EWRAW);
    int*    degIn = (int*)(R + A_DEGIN);
    int*    degOut= (int*)(R + A_DEGOUT);
    int*    cursor= (int*)(R + A_CURSOR);
    float*  HS    = (float*)(R + A_HS);
    float*  AGG   = (float*)(R + A_AGG);
    float*  Z     = (float*)(R + A_Z);
    float*  Wt    = (float*)(R + A_WT);

    const int g = blockIdx.x;
    const int t = threadIdx.x;

    // ---------- phase E: degrees + counting-sort edges by dst ----------
    if (t < NPG) {
        degIn[t] = 0; degOut[t] = 0;
        const int gn = g * NPG + t;
        nid[t] = node_id[gn];
        fid[t] = feats[gn];
    }
    __syncthreads();
    for (int e = t; e < EPG; e += 512) {
        const int ge = g * EPG + e;
        const int s = src[ge] - g * NPG;
        const int d = dst[ge] - g * NPG;
        rawSD[e] = (uint)s | ((uint)d << 16);
        ewRaw[e] = edata[edge_id[ge]];
        atomicAdd(&degOut[s], 1);
        atomicAdd(&degIn[d], 1);
    }
    __syncthreads();
    if (t < NPG) rowS[t + 1] = degIn[t];
    if (t == 0)  rowS[0] = 0;
    __syncthreads();
    for (int off = 1; off < NPG; off <<= 1) {
        int add = 0;
        if (t < NPG && t >= off) add = rowS[t + 1 - off];
        __syncthreads();
        if (t < NPG && t >= off) rowS[t + 1] += add;
        __syncthreads();
    }
    if (t < NPG) {
        ns[t] = (float)(1.0 / sqrt((double)(degOut[t] > 0 ? degOut[t] : 1)));
        nd[t] = (float)(1.0 / sqrt((double)(degIn[t]  > 0 ? degIn[t]  : 1)));
        cursor[t] = rowS[t];
    }
    __syncthreads();
    for (int e = t; e < EPG; e += 512) {
        const uint sd = rawSD[e];
        const int d = (int)(sd >> 16), s = (int)(sd & 0xffffu);
        const int pos = atomicAdd(&cursor[d], 1);
        sSrc[pos] = (ushort)s;
        sEw[pos]  = ewRaw[e];
    }
    __syncthreads();

    // ---------- Layer 1 (128 -> 32), 4 chunks of 32 dims ----------
    for (int i = t; i < NPG * HID; i += 512) Z[i] = 0.f;
    for (int c = 0; c < 4; ++c) {
        for (int i = t; i < 1024; i += 512) Wt[i] = W0[c * 1024 + i];
        for (int i = t; i < NPG * 8; i += 512) {
            const int n = i >> 3, q = i & 7;
            const int j0 = c * 32 + q * 4;
            float4 v;
            if (j0 < 64)      v = *(const float4*)(ndata    + (size_t)nid[n] * 64 + j0);
            else if (j0 < 96) v = *(const float4*)(node_emb + (size_t)fid[n] * 32 + (j0 - 64));
            else              v = *(const float4*)(node_emb + (size_t)(NATTR + nid[n]) * 32 + (j0 - 96));
            const float sc = ns[n];
            float4 o; o.x = v.x * sc; o.y = v.y * sc; o.z = v.z * sc; o.w = v.w * sc;
            *(float4*)(HS + n * 36 + q * 4) = o;
        }
        __syncthreads();
        aggregate_edges(sSrc, sEw, rowS, HS, AGG, nd, t);
        __syncthreads();
        {
            const int j = t & 31, nb = t >> 5;
            float wc[32];
            #pragma unroll
            for (int d = 0; d < 32; ++d) wc[d] = Wt[d * 32 + j];
            for (int i2 = 0; i2 < 16; ++i2) {
                const int n = nb * 16 + i2;
                const float4* ar = (const float4*)(AGG + n * 36);
                float acc = 0.f;
                #pragma unroll
                for (int d8 = 0; d8 < 8; ++d8) {
                    const float4 a = ar[d8];
                    acc = fmaf(a.x, wc[4 * d8 + 0], acc);
                    acc = fmaf(a.y, wc[4 * d8 + 1], acc);
                    acc = fmaf(a.z, wc[4 * d8 + 2], acc);
                    acc = fmaf(a.w, wc[4 * d8 + 3], acc);
                }
                Z[n * 32 + j] += acc;
            }
        }
        __syncthreads();
    }
    {   // finalize h1
        const int j = t & 31;
        const float bj = b0[j];
        for (int idx = t; idx < NPG * HID; idx += 512) {
            const int n = idx >> 5;
            const float h = tanhf(Z[idx] + bj);
            g_feat[(size_t)(g * NPG + n) * DLAT + j] = h;
            HS[n * 36 + j] = h * ns[n];
        }
    }
    __syncthreads();

    // ---------- Layers 2 and 3 (32 -> 32) ----------
    for (int L = 0; L < 2; ++L) {
        const float* WL = (L == 0) ? W1 : W2;
        const float* bL = (L == 0) ? b1 : b2;
        const int off = 32 + L * 32;
        for (int i = t; i < 1024; i += 512) Wt[i] = WL[i];
        aggregate_edges(sSrc, sEw, rowS, HS, AGG, nd, t);
        __syncthreads();
        {
            const int j = t & 31, nb = t >> 5;
            float wc[32];
            #pragma unroll
            for (int d = 0; d < 32; ++d) wc[d] = Wt[d * 32 + j];
            const float bj = bL[j];
            for (int i2 = 0; i2 < 16; ++i2) {
                const int n = nb * 16 + i2;
                const float4* ar = (const float4*)(AGG + n * 36);
                float acc = 0.f;
                #pragma unroll
                for (int d8 = 0; d8 < 8; ++d8) {
                    const float4 a = ar[d8];
                    acc = fmaf(a.x, wc[4 * d8 + 0], acc);
                    acc = fmaf(a.y, wc[4 * d8 + 1], acc);
                    acc = fmaf(a.z, wc[4 * d8 + 2], acc);
                    acc = fmaf(a.w, wc[4 * d8 + 3], acc);
                }
                const float h = tanhf(acc + bj);
                g_feat[(size_t)(g * NPG + n) * DLAT + off + j] = h;
                HS[n * 36 + j] = h * ns[n];
            }
        }
        __syncthreads();
    }

    // ---------- Layer 4 (32 -> 1) ----------
    if (t < 32) Wt[t] = W3[t];
    aggregate_edges(sSrc, sEw, rowS, HS, AGG, nd, t);
    __syncthreads();
    if (t < NPG) {
        float acc = 0.f;
        #pragma unroll
        for (int d = 0; d < 32; ++d) acc = fmaf(AGG[t * 36 + d], Wt[d], acc);
        const float h = tanhf(acc + b3[0]);
        g_feat[(size_t)(g * NPG + t) * DLAT + 96] = h;
    }
}

// ---------------- Kernel B LDS layout ----------------
#define B_SF    0         // float[256*100] 102400
#define B_KEYS  102400    // float[256]
#define B_SEL   103424    // int[32]
#define B_C1W   103552    // float[16*97]  6208
#define B_C2W   109760    // float[2560]  10240
#define B_L1    120000    // float[480]
#define B_Q     121920    // float[240]
#define B_RR    122880    // float[352]
#define B_FF    124288    // float[128]
#define B_TOTAL 124800

extern "C" __global__ void __launch_bounds__(512, 1)
head_kernel(const float* __restrict__ c1w, const float* __restrict__ c1b,
            const float* __restrict__ c2w, const float* __restrict__ c2b,
            const float* __restrict__ f1w, const float* __restrict__ f1b,
            const float* __restrict__ f2w, const float* __restrict__ f2b,
            float* __restrict__ out)
{
    extern __shared__ char smem[];
    float* SF    = (float*)(smem + B_SF);
    float* keysV = (float*)(smem + B_KEYS);
    int*   selI  = (int*)(smem + B_SEL);
    float* c1wS  = (float*)(smem + B_C1W);
    float* c2wS  = (float*)(smem + B_C2W);
    float* L1    = (float*)(smem + B_L1);
    float* Q     = (float*)(smem + B_Q);
    float* Rr    = (float*)(smem + B_RR);
    float* Ff    = (float*)(smem + B_FF);

    const int g = blockIdx.x, t = threadIdx.x;
    const int lane = t & 63, wv = t >> 6;

    for (int i = t; i < 16 * 97; i += 512) c1wS[i] = c1w[i];
    for (int i = t; i < 2560;    i += 512) c2wS[i] = c2w[i];

    // per-node bitonic-128 sort (ascending), pads = +inf at the top
    for (int n = wv; n < NPG; n += 8) {
        const float* fr = g_feat + (size_t)(g * NPG + n) * DLAT;
        float v0 = fr[lane];
        float v1 = (lane < 33) ? fr[64 + lane] : INFINITY;
        for (int k = 2; k <= 128; k <<= 1) {
            for (int j = k >> 1; j > 0; j >>= 1) {
                if (j == 64) {          // only in final merge (k==128): ascending
                    const float lo = fminf(v0, v1), hi = fmaxf(v0, v1);
                    v0 = lo; v1 = hi;
                } else {
                    const float p0 = __shfl_xor(v0, j, 64);
                    const float p1 = __shfl_xor(v1, j, 64);
                    const bool up   = ((lane & j) == 0);
                    const bool asc0 = (k == 128) ? true : ((lane & k) == 0);
                    const bool asc1 = (k == 128) ? true : (((64 + lane) & k) == 0);
                    v0 = (up == asc0) ? fminf(v0, p0) : fmaxf(v0, p0);
                    v1 = (up == asc1) ? fminf(v1, p1) : fmaxf(v1, p1);
                }
            }
        }
        SF[n * 100 + lane] = v0;
        if (lane < 33) SF[n * 100 + 64 + lane] = v1;
    }
    __syncthreads();
    if (t < NPG) keysV[t] = SF[t * 100 + 96];   // max feature per node
    __syncthreads();

    // top-30: jax.lax.top_k semantics (desc value, ties -> lower index first)
    if (wv == 0) {
        float kv[4]; int ki[4];
        #pragma unroll
        for (int r = 0; r < 4; ++r) { ki[r] = lane * 4 + r; kv[r] = keysV[lane * 4 + r]; }
        for (int it = 0; it < 30; ++it) {
            float bv = kv[0]; int bi = ki[0];
            #pragma unroll
            for (int r = 1; r < 4; ++r)
                if (kv[r] > bv || (kv[r] == bv && ki[r] < bi)) { bv = kv[r]; bi = ki[r]; }
            #pragma unroll
            for (int off = 1; off <= 32; off <<= 1) {
                const float ov = __shfl_xor(bv, off, 64);
                const int   oi = __shfl_xor(bi, off, 64);
                if (ov > bv || (ov == bv && oi < bi)) { bv = ov; bi = oi; }
            }
            if (lane == 0) selI[it] = bi;
            if ((bi >> 2) == lane) kv[bi & 3] = -INFINITY;
        }
    }
    __syncthreads();

    // conv1 (16 ch, kernel 97, stride 97) + relu
    if (t < 480) {
        const int k = t >> 4, c = t & 15;
        const float* row  = SF + selI[k] * 100;
        const float* wrow = c1wS + c * 97;
        float acc = c1b[c];
        for (int d = 0; d < 97; ++d) acc = fmaf(row[d], wrow[d], acc);
        L1[k * 16 + c] = fmaxf(acc, 0.f);
    }
    __syncthreads();
    // maxpool /2
    if (t < 240) {
        const int c = t / 15, tt = t % 15;
        Q[c * 15 + tt] = fmaxf(L1[(2 * tt) * 16 + c], L1[(2 * tt + 1) * 16 + c]);
    }
    __syncthreads();
    // conv2 (32 ch, kernel 5) + relu
    if (t < 352) {
        const int o = t / 11, tt = t % 11;
        const float* wo = c2wS + o * 80;
        float acc = c2b[o];
        #pragma unroll
        for (int c = 0; c < 16; ++c)
            #pragma unroll
            for (int j = 0; j < 5; ++j)
                acc = fmaf(Q[c * 15 + tt + j], wo[c * 5 + j], acc);
        Rr[o * 11 + tt] = fmaxf(acc, 0.f);
    }
    __syncthreads();
    // fc1 + relu
    if (t < 128) {
        float acc = f1b[t];
        const float* wr = f1w + t * 352;
        for (int i = 0; i < 352; ++i) acc = fmaf(Rr[i], wr[i], acc);
        Ff[t] = fmaxf(acc, 0.f);
    }
    __syncthreads();
    // fc2
    if (wv == 0) {
        float acc = Ff[lane] * f2w[lane] + Ff[lane + 64] * f2w[lane + 64];
        #pragma unroll
        for (int off = 1; off <= 32; off <<= 1) acc += __shfl_xor(acc, off, 64);
        if (lane == 0) out[g] = acc + f2b[0];
    }
}

extern "C" void kernel_launch(void* const* d_in, const int* in_sizes, int n_in,
                              void* d_out, int out_size, void* d_ws, size_t ws_size,
                              hipStream_t stream)
{
    const int*   feats    = (const int*)d_in[0];
    const int*   node_id  = (const int*)d_in[1];
    const int*   edge_id  = (const int*)d_in[2];
    const int*   src      = (const int*)d_in[3];
    const int*   dst      = (const int*)d_in[4];
    const float* ndata    = (const float*)d_in[5];
    const float* edata    = (const float*)d_in[6];
    const float* node_emb = (const float*)d_in[7];
    const float* W0 = (const float*)d_in[8];
    const float* b0 = (const float*)d_in[9];
    const float* W1 = (const float*)d_in[10];
    const float* b1 = (const float*)d_in[11];
    const float* W2 = (const float*)d_in[12];
    const float* b2 = (const float*)d_in[13];
    const float* W3 = (const float*)d_in[14];
    const float* b3 = (const float*)d_in[15];
    const float* c1w = (const float*)d_in[16];
    const float* c1b = (const float*)d_in[17];
    const float* c2w = (const float*)d_in[18];
    const float* c2b = (const float*)d_in[19];
    const float* f1w = (const float*)d_in[20];
    const float* f1b = (const float*)d_in[21];
    const float* f2w = (const float*)d_in[22];
    const float* f2b = (const float*)d_in[23];

    (void)hipFuncSetAttribute((const void*)gnn_layers,
                              hipFuncAttributeMaxDynamicSharedMemorySize, A_TOTAL);
    (void)hipFuncSetAttribute((const void*)head_kernel,
                              hipFuncAttributeMaxDynamicSharedMemorySize, B_TOTAL);

    gnn_layers<<<NGRAPH, 512, A_TOTAL, stream>>>(feats, node_id, edge_id, src, dst,
                                                 ndata, edata, node_emb,
                                                 W0, b0, W1, b1, W2, b2, W3, b3);
    head_kernel<<<NGRAPH, 512, B_TOTAL, stream>>>(c1w, c1b, c2w, c2b,
                                                  f1w, f1b, f2w, f2b,
                                                  (float*)d_out);
}

// Round 2
// 583.947 us; speedup vs baseline: 2.0989x; 2.0989x over previous
//
#include <hip/hip_runtime.h>
#include <hip/hip_bf16.h>
#include <math.h>

#define NPG    256
#define EPG    4096
#define NGRAPH 1024
#define NATTR  100000
#define HID    32
#define FROW   100   // padded row stride (97 used) so float4 stores stay aligned

// per-node 97-dim feature rows (padded to 100), ~105 MB
__device__ float g_feat[(size_t)NGRAPH * NPG * FROW];

// ---------------- Kernel A LDS layout (bytes) ----------------
#define A_SSRC   0        // ushort[4096]   8192
#define A_SEW    8192     // float[4096]   16384
#define A_ROWS   24576    // int[257]       1056 (padded)
#define A_NS     25664    // float[256]
#define A_ND     26688    // float[256]
#define A_NID    27712    // int[256]
#define A_FID    28736    // int[256]
#define A_BS     29760    // float[128] biases b0|b1|b2|b3
#define A_R      30272    // union region
// phase E (within R)
#define A_RAWSD  0        // uint[4096]   16384
#define A_EWRAW  16384    // float[4096]  16384
#define A_DEGI   32768    // int[256]
#define A_DEGO   33792    // int[256]
#define A_CUR    34816    // int[256]      (ends 35840)
// layer phase (within R)
#define A_Y      0        // float[256*36] 36864  (post-transform features y)
#define A_HS     36864    // float[256*36] 36864  (h * ns, matmul input)
#define A_WT     73728    // float[1024]    4096
#define A_RSZ    77824
#define A_TOTAL  (A_R + A_RSZ)   // 108096 bytes

// aggregate 32-dim Y over edges, activate, write g_feat (+ optionally HS = h*ns)
__device__ __forceinline__ void aggregate32(const ushort* sSrc, const float* sEw,
                                            const int* rowS, const float* Y,
                                            const float* ns, const float* nd,
                                            const float* Bs, int boff,
                                            float* HS, float* gout, int t)
{
    #pragma unroll
    for (int r = 0; r < 2; ++r) {
        const int n = r * 128 + (t >> 3);
        const int q = t & 7;
        const int rs = rowS[n], re = rowS[n + 1];
        double a0 = 0.0, a1 = 0.0, a2 = 0.0, a3 = 0.0;
        for (int e = rs; e < re; ++e) {
            const int s = sSrc[e];
            const double w = (double)sEw[e];
            const float4 y = *(const float4*)(Y + s * 36 + q * 4);
            a0 += (double)y.x * w;
            a1 += (double)y.y * w;
            a2 += (double)y.z * w;
            a3 += (double)y.w * w;
        }
        const double sc = (double)nd[n];
        const float h0 = tanhf((float)(a0 * sc) + Bs[boff + q * 4 + 0]);
        const float h1 = tanhf((float)(a1 * sc) + Bs[boff + q * 4 + 1]);
        const float h2 = tanhf((float)(a2 * sc) + Bs[boff + q * 4 + 2]);
        const float h3 = tanhf((float)(a3 * sc) + Bs[boff + q * 4 + 3]);
        float4 hv; hv.x = h0; hv.y = h1; hv.z = h2; hv.w = h3;
        *(float4*)(gout + (size_t)n * FROW + boff + q * 4) = hv;
        const float s2 = ns[n];
        float4 o; o.x = h0 * s2; o.y = h1 * s2; o.z = h2 * s2; o.w = h3 * s2;
        *(float4*)(HS + n * 36 + q * 4) = o;
    }
}

extern "C" __global__ void __launch_bounds__(1024, 4)
gnn_layers(const int* __restrict__ feats, const int* __restrict__ node_id,
           const int* __restrict__ edge_id, const int* __restrict__ src,
           const int* __restrict__ dst,
           const float* __restrict__ ndata, const float* __restrict__ edata,
           const float* __restrict__ node_emb,
           const float* __restrict__ W0, const float* __restrict__ b0,
           const float* __restrict__ W1, const float* __restrict__ b1,
           const float* __restrict__ W2, const float* __restrict__ b2,
           const float* __restrict__ W3, const float* __restrict__ b3)
{
    extern __shared__ char smem[];
    ushort* sSrc  = (ushort*)(smem + A_SSRC);
    float*  sEw   = (float*)(smem + A_SEW);
    int*    rowS  = (int*)(smem + A_ROWS);
    float*  ns    = (float*)(smem + A_NS);
    float*  nd    = (float*)(smem + A_ND);
    int*    nid   = (int*)(smem + A_NID);
    int*    fid   = (int*)(smem + A_FID);
    float*  Bs    = (float*)(smem + A_BS);
    char*   R     = smem + A_R;
    uint*   rawSD = (uint*)(R + A_RAWSD);
    float*  ewRaw = (float*)(R + A_EWRAW);
    int*    degI  = (int*)(R + A_DEGI);
    int*    degO  = (int*)(R + A_DEGO);
    int*    cur   = (int*)(R + A_CUR);
    float*  Y     = (float*)(R + A_Y);
    float*  HS    = (float*)(R + A_HS);
    float*  Wt    = (float*)(R + A_WT);

    const int g = blockIdx.x;
    const int t = threadIdx.x;
    float* gF = g_feat + (size_t)g * NPG * FROW;

    // ---------- phase E: degrees + counting-sort edges by dst ----------
    if (t < NPG) {
        degI[t] = 0; degO[t] = 0;
        const int gn = g * NPG + t;
        nid[t] = node_id[gn];
        fid[t] = feats[gn];
    }
    if (t < 97) Bs[t] = (t < 32) ? b0[t] : (t < 64) ? b1[t - 32]
                       : (t < 96) ? b2[t - 64] : b3[0];
    __syncthreads();
    for (int e = t; e < EPG; e += 1024) {
        const int ge = g * EPG + e;
        const int s = src[ge] - g * NPG;
        const int d = dst[ge] - g * NPG;
        rawSD[e] = (uint)s | ((uint)d << 16);
        ewRaw[e] = edata[edge_id[ge]];
        atomicAdd(&degO[s], 1);
        atomicAdd(&degI[d], 1);
    }
    __syncthreads();
    if (t < NPG) rowS[t + 1] = degI[t];
    if (t == 0)  rowS[0] = 0;
    __syncthreads();
    for (int off = 1; off < NPG; off <<= 1) {
        int add = 0;
        if (t < NPG && t >= off) add = rowS[t + 1 - off];
        __syncthreads();
        if (t < NPG && t >= off) rowS[t + 1] += add;
        __syncthreads();
    }
    if (t < NPG) {
        ns[t] = (float)(1.0 / sqrt((double)(degO[t] > 0 ? degO[t] : 1)));
        nd[t] = (float)(1.0 / sqrt((double)(degI[t] > 0 ? degI[t] : 1)));
        cur[t] = rowS[t];
    }
    __syncthreads();
    for (int e = t; e < EPG; e += 1024) {
        const uint sd = rawSD[e];
        const int d = (int)(sd >> 16), s = (int)(sd & 0xffffu);
        const int pos = atomicAdd(&cur[d], 1);
        sSrc[pos] = (ushort)s;
        sEw[pos]  = ewRaw[e];
    }
    __syncthreads();

    const int j = t & 31, nb = t >> 5;   // matmul mapping: thread -> (node block, out dim)

    // ---------- Layer 1: y = (x*ns) @ W0 via 4 input chunks, then aggregate ----------
    {
        float acc[8] = {0.f, 0.f, 0.f, 0.f, 0.f, 0.f, 0.f, 0.f};
        for (int c = 0; c < 4; ++c) {
            for (int i = t; i < 2048; i += 1024) {
                const int n = i >> 3, q = i & 7;
                const int j0 = c * 32 + q * 4;
                float4 v;
                if (j0 < 64)      v = *(const float4*)(ndata    + (size_t)nid[n] * 64 + j0);
                else if (j0 < 96) v = *(const float4*)(node_emb + (size_t)fid[n] * 32 + (j0 - 64));
                else              v = *(const float4*)(node_emb + (size_t)(NATTR + nid[n]) * 32 + (j0 - 96));
                const float sc = ns[n];
                float4 o; o.x = v.x * sc; o.y = v.y * sc; o.z = v.z * sc; o.w = v.w * sc;
                *(float4*)(HS + n * 36 + q * 4) = o;
            }
            Wt[t] = W0[c * 1024 + t];
            __syncthreads();
            float wc[32];
            #pragma unroll
            for (int d = 0; d < 32; ++d) wc[d] = Wt[d * 32 + j];
            #pragma unroll
            for (int i2 = 0; i2 < 8; ++i2) {
                const int n = nb * 8 + i2;
                const float4* ar = (const float4*)(HS + n * 36);
                float a = acc[i2];
                #pragma unroll
                for (int d8 = 0; d8 < 8; ++d8) {
                    const float4 av = ar[d8];
                    a = fmaf(av.x, wc[4 * d8 + 0], a);
                    a = fmaf(av.y, wc[4 * d8 + 1], a);
                    a = fmaf(av.z, wc[4 * d8 + 2], a);
                    a = fmaf(av.w, wc[4 * d8 + 3], a);
                }
                acc[i2] = a;
            }
            __syncthreads();   // HS reused next chunk
        }
        #pragma unroll
        for (int i2 = 0; i2 < 8; ++i2) Y[(nb * 8 + i2) * 36 + j] = acc[i2];
        __syncthreads();
        aggregate32(sSrc, sEw, rowS, Y, ns, nd, Bs, 0, HS, gF, t);
        __syncthreads();
    }

    // ---------- Layers 2, 3: y = HS @ W, aggregate ----------
    for (int L = 0; L < 2; ++L) {
        Wt[t] = (L == 0) ? W1[t] : W2[t];
        __syncthreads();
        float wc[32];
        #pragma unroll
        for (int d = 0; d < 32; ++d) wc[d] = Wt[d * 32 + j];
        float acc[8];
        #pragma unroll
        for (int i2 = 0; i2 < 8; ++i2) {
            const int n = nb * 8 + i2;
            const float4* ar = (const float4*)(HS + n * 36);
            float a = 0.f;
            #pragma unroll
            for (int d8 = 0; d8 < 8; ++d8) {
                const float4 av = ar[d8];
                a = fmaf(av.x, wc[4 * d8 + 0], a);
                a = fmaf(av.y, wc[4 * d8 + 1], a);
                a = fmaf(av.z, wc[4 * d8 + 2], a);
                a = fmaf(av.w, wc[4 * d8 + 3], a);
            }
            acc[i2] = a;
        }
        #pragma unroll
        for (int i2 = 0; i2 < 8; ++i2) Y[(nb * 8 + i2) * 36 + j] = acc[i2];
        __syncthreads();
        aggregate32(sSrc, sEw, rowS, Y, ns, nd, Bs, 32 + L * 32, HS, gF, t);
        __syncthreads();
    }

    // ---------- Layer 4: y4 = HS @ W3 (scalar), aggregate ----------
    if (t < 32) Wt[t] = W3[t];
    __syncthreads();
    if (t < NPG) {
        const float4* hr = (const float4*)(HS + t * 36);
        float a = 0.f;
        #pragma unroll
        for (int d8 = 0; d8 < 8; ++d8) {
            const float4 h = hr[d8];
            a = fmaf(h.x, Wt[4 * d8 + 0], a);
            a = fmaf(h.y, Wt[4 * d8 + 1], a);
            a = fmaf(h.z, Wt[4 * d8 + 2], a);
            a = fmaf(h.w, Wt[4 * d8 + 3], a);
        }
        Y[t] = a;
    }
    __syncthreads();
    if (t < NPG) {
        const int rs = rowS[t], re = rowS[t + 1];
        double a = 0.0;
        for (int e = rs; e < re; ++e)
            a += (double)sEw[e] * (double)Y[sSrc[e]];
        const float h = tanhf((float)(a * (double)nd[t]) + Bs[96]);
        gF[(size_t)t * FROW + 96] = h;
    }
}

// ---------------- Kernel B LDS layout ----------------
#define B_SF    0         // float[256*100] 102400
#define B_KEYS  102400    // float[256]
#define B_SEL   103424    // int[32]
#define B_C1W   103552    // float[16*97]  6208
#define B_C2W   109760    // float[2560]  10240
#define B_L1    120000    // float[480]
#define B_Q     121920    // float[240]
#define B_RR    122880    // float[352]
#define B_FF    124288    // float[128]
#define B_TOTAL 124800

extern "C" __global__ void __launch_bounds__(1024, 4)
head_kernel(const float* __restrict__ c1w, const float* __restrict__ c1b,
            const float* __restrict__ c2w, const float* __restrict__ c2b,
            const float* __restrict__ f1w, const float* __restrict__ f1b,
            const float* __restrict__ f2w, const float* __restrict__ f2b,
            float* __restrict__ out)
{
    extern __shared__ char smem[];
    float* SF    = (float*)(smem + B_SF);
    float* keysV = (float*)(smem + B_KEYS);
    int*   selI  = (int*)(smem + B_SEL);
    float* c1wS  = (float*)(smem + B_C1W);
    float* c2wS  = (float*)(smem + B_C2W);
    float* L1    = (float*)(smem + B_L1);
    float* Q     = (float*)(smem + B_Q);
    float* Rr    = (float*)(smem + B_RR);
    float* Ff    = (float*)(smem + B_FF);

    const int g = blockIdx.x, t = threadIdx.x;
    const int lane = t & 63, wv = t >> 6;

    for (int i = t; i < 16 * 97; i += 1024) c1wS[i] = c1w[i];
    for (int i = t; i < 2560;    i += 1024) c2wS[i] = c2w[i];

    // per-node bitonic-128 sort (ascending), pads = +inf at the top
    for (int n = wv; n < NPG; n += 16) {
        const float* fr = g_feat + (size_t)(g * NPG + n) * FROW;
        float v0 = fr[lane];
        float v1 = (lane < 33) ? fr[64 + lane] : INFINITY;
        for (int k = 2; k <= 128; k <<= 1) {
            for (int jj = k >> 1; jj > 0; jj >>= 1) {
                if (jj == 64) {          // only in final merge (k==128): ascending
                    const float lo = fminf(v0, v1), hi = fmaxf(v0, v1);
                    v0 = lo; v1 = hi;
                } else {
                    const float p0 = __shfl_xor(v0, jj, 64);
                    const float p1 = __shfl_xor(v1, jj, 64);
                    const bool up   = ((lane & jj) == 0);
                    const bool asc0 = (k == 128) ? true : ((lane & k) == 0);
                    const bool asc1 = (k == 128) ? true : (((64 + lane) & k) == 0);
                    v0 = (up == asc0) ? fminf(v0, p0) : fmaxf(v0, p0);
                    v1 = (up == asc1) ? fminf(v1, p1) : fmaxf(v1, p1);
                }
            }
        }
        SF[n * 100 + lane] = v0;
        if (lane < 33) SF[n * 100 + 64 + lane] = v1;
    }
    __syncthreads();
    if (t < NPG) keysV[t] = SF[t * 100 + 96];   // max feature per node
    __syncthreads();

    // top-30: jax.lax.top_k semantics (desc value, ties -> lower index first)
    if (wv == 0) {
        float kv[4]; int ki[4];
        #pragma unroll
        for (int r = 0; r < 4; ++r) { ki[r] = lane * 4 + r; kv[r] = keysV[lane * 4 + r]; }
        for (int it = 0; it < 30; ++it) {
            float bv = kv[0]; int bi = ki[0];
            #pragma unroll
            for (int r = 1; r < 4; ++r)
                if (kv[r] > bv || (kv[r] == bv && ki[r] < bi)) { bv = kv[r]; bi = ki[r]; }
            #pragma unroll
            for (int off = 1; off <= 32; off <<= 1) {
                const float ov = __shfl_xor(bv, off, 64);
                const int   oi = __shfl_xor(bi, off, 64);
                if (ov > bv || (ov == bv && oi < bi)) { bv = ov; bi = oi; }
            }
            if (lane == 0) selI[it] = bi;
            if ((bi >> 2) == lane) kv[bi & 3] = -INFINITY;
        }
    }
    __syncthreads();

    // conv1 (16 ch, kernel 97, stride 97) + relu
    if (t < 480) {
        const int k = t >> 4, c = t & 15;
        const float* row  = SF + selI[k] * 100;
        const float* wrow = c1wS + c * 97;
        float acc = c1b[c];
        for (int d = 0; d < 97; ++d) acc = fmaf(row[d], wrow[d], acc);
        L1[k * 16 + c] = fmaxf(acc, 0.f);
    }
    __syncthreads();
    // maxpool /2
    if (t < 240) {
        const int c = t / 15, tt = t % 15;
        Q[c * 15 + tt] = fmaxf(L1[(2 * tt) * 16 + c], L1[(2 * tt + 1) * 16 + c]);
    }
    __syncthreads();
    // conv2 (32 ch, kernel 5) + relu
    if (t < 352) {
        const int o = t / 11, tt = t % 11;
        const float* wo = c2wS + o * 80;
        float acc = c2b[o];
        #pragma unroll
        for (int c = 0; c < 16; ++c)
            #pragma unroll
            for (int jj = 0; jj < 5; ++jj)
                acc = fmaf(Q[c * 15 + tt + jj], wo[c * 5 + jj], acc);
        Rr[o * 11 + tt] = fmaxf(acc, 0.f);
    }
    __syncthreads();
    // fc1 + relu
    if (t < 128) {
        float acc = f1b[t];
        const float* wr = f1w + t * 352;
        for (int i = 0; i < 352; ++i) acc = fmaf(Rr[i], wr[i], acc);
        Ff[t] = fmaxf(acc, 0.f);
    }
    __syncthreads();
    // fc2
    if (wv == 0) {
        float acc = Ff[lane] * f2w[lane] + Ff[lane + 64] * f2w[lane + 64];
        #pragma unroll
        for (int off = 1; off <= 32; off <<= 1) acc += __shfl_xor(acc, off, 64);
        if (lane == 0) out[g] = acc + f2b[0];
    }
}

extern "C" void kernel_launch(void* const* d_in, const int* in_sizes, int n_in,
                              void* d_out, int out_size, void* d_ws, size_t ws_size,
                              hipStream_t stream)
{
    const int*   feats    = (const int*)d_in[0];
    const int*   node_id  = (const int*)d_in[1];
    const int*   edge_id  = (const int*)d_in[2];
    const int*   src      = (const int*)d_in[3];
    const int*   dst      = (const int*)d_in[4];
    const float* ndata    = (const float*)d_in[5];
    const float* edata    = (const float*)d_in[6];
    const float* node_emb = (const float*)d_in[7];
    const float* W0 = (const float*)d_in[8];
    const float* b0 = (const float*)d_in[9];
    const float* W1 = (const float*)d_in[10];
    const float* b1 = (const float*)d_in[11];
    const float* W2 = (const float*)d_in[12];
    const float* b2 = (const float*)d_in[13];
    const float* W3 = (const float*)d_in[14];
    const float* b3 = (const float*)d_in[15];
    const float* c1w = (const float*)d_in[16];
    const float* c1b = (const float*)d_in[17];
    const float* c2w = (const float*)d_in[18];
    const float* c2b = (const float*)d_in[19];
    const float* f1w = (const float*)d_in[20];
    const float* f1b = (const float*)d_in[21];
    const float* f2w = (const float*)d_in[22];
    const float* f2b = (const float*)d_in[23];

    (void)hipFuncSetAttribute((const void*)gnn_layers,
                              hipFuncAttributeMaxDynamicSharedMemorySize, A_TOTAL);
    (void)hipFuncSetAttribute((const void*)head_kernel,
                              hipFuncAttributeMaxDynamicSharedMemorySize, B_TOTAL);

    gnn_layers<<<NGRAPH, 1024, A_TOTAL, stream>>>(feats, node_id, edge_id, src, dst,
                                                  ndata, edata, node_emb,
                                                  W0, b0, W1, b1, W2, b2, W3, b3);
    head_kernel<<<NGRAPH, 1024, B_TOTAL, stream>>>(c1w, c1b, c2w, c2b,
                                                   f1w, f1b, f2w, f2b,
                                                   (float*)d_out);
}

// Round 3
// 416.473 us; speedup vs baseline: 2.9429x; 1.4021x over previous
//
#include <hip/hip_runtime.h>
#include <math.h>

#define NPG    256
#define EPG    4096
#define NGRAPH 1024
#define NATTR  100000

// ---------------- LDS layout (bytes), total 163,384 <= 163,840 ----------------
#define A_F      0         // float[256][100] 102400 : per-node 97-dim features (stride 100, 16B-aligned rows)
#define A_YR     102400    // 36864 : union region (phase-E scratch | x-staging/Y stride-36 | head scratch)
#define A_EW     139264    // float[4100] 16400 : edge weights, dst-sorted (+sentinel)
#define A_SRC    155664    // uchar[4104] 4104 : edge src u8, dst-sorted (+sentinel); later keys/selI
#define A_ROWS   159768    // int[257] 1056
#define A_NS     160824    // float[256]
#define A_ND     161848    // float[256]
#define A_BS     162872    // float[128] biases b0|b1|b2|b3
#define A_TOTAL  163384

// phase-E scratch inside YR
#define E_RAWSD  0         // uint[4096]
#define E_EWRAW  16384     // float[4096]
#define E_DEGI   32768     // int[256]
#define E_DEGO   33792     // int[256]
#define E_CUR    34816     // int[256]   (end 35840)

// head scratch inside YR
#define H_S30    0         // float[30][100] 12000 (sorted selected rows)
#define H_C1W    12000     // float[1552]
#define H_C2W    18208     // float[2560]
#define H_L1     28448     // float[480]
#define H_Q      30368     // float[240]
#define H_RR     31328     // float[352]
#define H_FF     32736     // float[128]  (end 33248)

// aggregate 32-dim Y (stride 36) over dst-sorted edges with 1-deep prefetch,
// tanh-activate, write h into F at column offset boff.
__device__ __forceinline__ void aggregate32(const unsigned char* sSrc, const float* sEw,
                                            const int* rowS, const float* Y,
                                            const float* nd, const float* Bs, int boff,
                                            float* F, int t)
{
    #pragma unroll
    for (int r = 0; r < 2; ++r) {
        const int n = r * 128 + (t >> 3);
        const int q = t & 7;
        const int rs = rowS[n], re = rowS[n + 1];
        double a0 = 0.0, a1 = 0.0, a2 = 0.0, a3 = 0.0;
        // prefetch slot 0 (sentinel-safe even when rs==re)
        int   s0 = sSrc[rs];
        float w0 = sEw[rs];
        float4 y0 = *(const float4*)(Y + s0 * 36 + q * 4);
        for (int e = rs; e < re; ++e) {
            const int   s1 = sSrc[e + 1];            // sentinel-padded at 4096
            const float w1 = sEw[e + 1];
            const float4 y1 = *(const float4*)(Y + s1 * 36 + q * 4);
            a0 += (double)y0.x * (double)w0;
            a1 += (double)y0.y * (double)w0;
            a2 += (double)y0.z * (double)w0;
            a3 += (double)y0.w * (double)w0;
            y0 = y1; w0 = w1;
        }
        const double sc = (double)nd[n];
        float4 hv;
        hv.x = tanhf((float)(a0 * sc) + Bs[boff + q * 4 + 0]);
        hv.y = tanhf((float)(a1 * sc) + Bs[boff + q * 4 + 1]);
        hv.z = tanhf((float)(a2 * sc) + Bs[boff + q * 4 + 2]);
        hv.w = tanhf((float)(a3 * sc) + Bs[boff + q * 4 + 3]);
        *(float4*)(F + n * 100 + boff + q * 4) = hv;
    }
}

extern "C" __global__ void __launch_bounds__(1024)
dgcnn_fused(const int* __restrict__ feats, const int* __restrict__ node_id,
            const int* __restrict__ edge_id, const int* __restrict__ src,
            const int* __restrict__ dst,
            const float* __restrict__ ndata, const float* __restrict__ edata,
            const float* __restrict__ node_emb,
            const float* __restrict__ W0, const float* __restrict__ b0,
            const float* __restrict__ W1, const float* __restrict__ b1,
            const float* __restrict__ W2, const float* __restrict__ b2,
            const float* __restrict__ W3, const float* __restrict__ b3,
            const float* __restrict__ c1w, const float* __restrict__ c1b,
            const float* __restrict__ c2w, const float* __restrict__ c2b,
            const float* __restrict__ f1w, const float* __restrict__ f1b,
            const float* __restrict__ f2w, const float* __restrict__ f2b,
            float* __restrict__ out)
{
    extern __shared__ char smem[];
    float* F   = (float*)(smem + A_F);
    char*  YRc = smem + A_YR;
    float* Y   = (float*)YRc;                       // stride-36 staging / transformed features
    float* sEw = (float*)(smem + A_EW);
    unsigned char* sSrc = (unsigned char*)(smem + A_SRC);
    int*   rowS = (int*)(smem + A_ROWS);
    float* ns   = (float*)(smem + A_NS);
    float* nd   = (float*)(smem + A_ND);
    float* Bs   = (float*)(smem + A_BS);

    uint*  rawSD = (uint*)(YRc + E_RAWSD);
    float* ewRaw = (float*)(YRc + E_EWRAW);
    int*   degI  = (int*)(YRc + E_DEGI);
    int*   degO  = (int*)(YRc + E_DEGO);
    int*   cur   = (int*)(YRc + E_CUR);

    const int g = blockIdx.x, t = threadIdx.x;
    const int lane = t & 63, wv = t >> 6;

    // ---------------- phase E: degrees + counting-sort edges by dst ----------------
    if (t < NPG) { degI[t] = 0; degO[t] = 0; }
    if (t < 97) Bs[t] = (t < 32) ? b0[t] : (t < 64) ? b1[t - 32]
                       : (t < 96) ? b2[t - 64] : b3[0];
    if (t < 4) { sSrc[4096 + t] = 0; sEw[4096 + t] = 0.f; }   // prefetch sentinels
    __syncthreads();
    for (int e = t; e < EPG; e += 1024) {
        const int ge = g * EPG + e;
        const int s = src[ge] - g * NPG;
        const int d = dst[ge] - g * NPG;
        rawSD[e] = (uint)s | ((uint)d << 16);
        ewRaw[e] = edata[edge_id[ge]];
        atomicAdd(&degO[s], 1);
        atomicAdd(&degI[d], 1);
    }
    __syncthreads();
    if (t < NPG) rowS[t + 1] = degI[t];
    if (t == 0)  rowS[0] = 0;
    __syncthreads();
    for (int off = 1; off < NPG; off <<= 1) {
        int add = 0;
        if (t < NPG && t >= off) add = rowS[t + 1 - off];
        __syncthreads();
        if (t < NPG && t >= off) rowS[t + 1] += add;
        __syncthreads();
    }
    if (t < NPG) {
        ns[t] = (float)(1.0 / sqrt((double)(degO[t] > 0 ? degO[t] : 1)));
        nd[t] = (float)(1.0 / sqrt((double)(degI[t] > 0 ? degI[t] : 1)));
        cur[t] = rowS[t];
    }
    __syncthreads();
    for (int e = t; e < EPG; e += 1024) {
        const uint sd = rawSD[e];
        const int d = (int)(sd >> 16), s = (int)(sd & 0xffffu);
        const int pos = atomicAdd(&cur[d], 1);
        sSrc[pos] = (unsigned char)s;
        sEw[pos]  = ewRaw[e];
    }
    __syncthreads();

    const int j = t & 31, nb = t >> 5;

    // ---------------- Layer 1: y = (x*ns) @ W0 via 4 input chunks ----------------
    {
        float acc[8] = {0.f, 0.f, 0.f, 0.f, 0.f, 0.f, 0.f, 0.f};
        for (int c = 0; c < 4; ++c) {
            for (int i = t; i < 2048; i += 1024) {
                const int n = i >> 3, q = i & 7;
                const int gn = g * NPG + n;
                const int nidn = node_id[gn];
                const int j0 = c * 32 + q * 4;
                float4 v;
                if (j0 < 64)      v = *(const float4*)(ndata    + (size_t)nidn * 64 + j0);
                else if (j0 < 96) v = *(const float4*)(node_emb + (size_t)feats[gn] * 32 + (j0 - 64));
                else              v = *(const float4*)(node_emb + (size_t)(NATTR + nidn) * 32 + (j0 - 96));
                const float sc = ns[n];
                float4 o; o.x = v.x * sc; o.y = v.y * sc; o.z = v.z * sc; o.w = v.w * sc;
                *(float4*)(Y + n * 36 + q * 4) = o;
            }
            __syncthreads();
            float wc[32];
            #pragma unroll
            for (int d = 0; d < 32; ++d) wc[d] = W0[(c * 32 + d) * 32 + j];
            #pragma unroll
            for (int i2 = 0; i2 < 8; ++i2) {
                const int n = nb * 8 + i2;
                const float4* ar = (const float4*)(Y + n * 36);
                float a = acc[i2];
                #pragma unroll
                for (int d8 = 0; d8 < 8; ++d8) {
                    const float4 av = ar[d8];
                    a = fmaf(av.x, wc[4 * d8 + 0], a);
                    a = fmaf(av.y, wc[4 * d8 + 1], a);
                    a = fmaf(av.z, wc[4 * d8 + 2], a);
                    a = fmaf(av.w, wc[4 * d8 + 3], a);
                }
                acc[i2] = a;
            }
            __syncthreads();
        }
        #pragma unroll
        for (int i2 = 0; i2 < 8; ++i2) Y[(nb * 8 + i2) * 36 + j] = acc[i2];
        __syncthreads();
        aggregate32(sSrc, sEw, rowS, Y, nd, Bs, 0, F, t);
        __syncthreads();
    }

    // ---------------- Layers 2, 3: y = (h*ns) @ W ----------------
    for (int L = 0; L < 2; ++L) {
        const float* WL = L ? W2 : W1;
        const int pb = L ? 32 : 0;           // previous layer's column offset in F
        float wc[32];
        #pragma unroll
        for (int d = 0; d < 32; ++d) wc[d] = WL[d * 32 + j];
        float acc[8];
        #pragma unroll
        for (int i2 = 0; i2 < 8; ++i2) {
            const int n = nb * 8 + i2;
            const float4* fr = (const float4*)(F + n * 100 + pb);
            float a = 0.f;
            #pragma unroll
            for (int d8 = 0; d8 < 8; ++d8) {
                const float4 av = fr[d8];
                a = fmaf(av.x, wc[4 * d8 + 0], a);
                a = fmaf(av.y, wc[4 * d8 + 1], a);
                a = fmaf(av.z, wc[4 * d8 + 2], a);
                a = fmaf(av.w, wc[4 * d8 + 3], a);
            }
            acc[i2] = a * ns[n];
        }
        #pragma unroll
        for (int i2 = 0; i2 < 8; ++i2) Y[(nb * 8 + i2) * 36 + j] = acc[i2];
        __syncthreads();
        aggregate32(sSrc, sEw, rowS, Y, nd, Bs, 32 + L * 32, F, t);
        __syncthreads();
    }

    // ---------------- Layer 4: scalar y4 = (h3*ns) @ W3, aggregate ----------------
    if (t < NPG) {
        const float4* fr = (const float4*)(F + t * 100 + 64);
        float a = 0.f;
        #pragma unroll
        for (int d8 = 0; d8 < 8; ++d8) {
            const float4 h = fr[d8];
            a = fmaf(h.x, W3[4 * d8 + 0], a);
            a = fmaf(h.y, W3[4 * d8 + 1], a);
            a = fmaf(h.z, W3[4 * d8 + 2], a);
            a = fmaf(h.w, W3[4 * d8 + 3], a);
        }
        Y[t] = a * ns[t];
    }
    __syncthreads();
    {
        const int n = t >> 2, p = t & 3;
        const int rs = rowS[n], re = rowS[n + 1];
        double a = 0.0;
        for (int e = rs + p; e < re; e += 4)
            a += (double)sEw[e] * (double)Y[sSrc[e]];
        a += __shfl_xor(a, 1, 64);
        a += __shfl_xor(a, 2, 64);
        if (p == 0)
            F[n * 100 + 96] = tanhf((float)(a * (double)nd[n]) + Bs[96]);
    }
    __syncthreads();

    // ---------------- head: per-node max -> top-30 -> sort 30 rows -> CNN ----------------
    float* keys = (float*)(smem + A_SRC);           // sSrc dead now
    int*   selI = (int*)(smem + A_SRC + 1024);
    float* S30  = (float*)(YRc + H_S30);
    float* c1wS = (float*)(YRc + H_C1W);
    float* c2wS = (float*)(YRc + H_C2W);
    float* L1   = (float*)(YRc + H_L1);
    float* Q    = (float*)(YRc + H_Q);
    float* Rr   = (float*)(YRc + H_RR);
    float* Ff   = (float*)(YRc + H_FF);

    if (t < NPG) {
        const float* fr = F + t * 100;
        float m0 = fr[0], m1 = fr[1], m2 = fr[2], m3 = fr[3];
        for (int d = 4; d < 96; d += 4) {
            m0 = fmaxf(m0, fr[d]);     m1 = fmaxf(m1, fr[d + 1]);
            m2 = fmaxf(m2, fr[d + 2]); m3 = fmaxf(m3, fr[d + 3]);
        }
        keys[t] = fmaxf(fmaxf(fmaxf(m0, m1), fmaxf(m2, m3)), fr[96]);
    }
    __syncthreads();

    if (t < 64) {
        // wave 0: top-30, jax.lax.top_k tie semantics (desc value, asc index)
        float kv[4]; int ki[4];
        #pragma unroll
        for (int r = 0; r < 4; ++r) { ki[r] = lane * 4 + r; kv[r] = keys[lane * 4 + r]; }
        for (int it = 0; it < 30; ++it) {
            float bv = kv[0]; int bi = ki[0];
            #pragma unroll
            for (int r = 1; r < 4; ++r)
                if (kv[r] > bv || (kv[r] == bv && ki[r] < bi)) { bv = kv[r]; bi = ki[r]; }
            #pragma unroll
            for (int off = 1; off <= 32; off <<= 1) {
                const float ov = __shfl_xor(bv, off, 64);
                const int   oi = __shfl_xor(bi, off, 64);
                if (ov > bv || (ov == bv && oi < bi)) { bv = ov; bi = oi; }
            }
            if (lane == 0) selI[it] = bi;
            if ((bi >> 2) == lane) kv[bi & 3] = -INFINITY;
        }
    } else {
        for (int i = t - 64; i < 1552; i += 960) c1wS[i] = c1w[i];
        for (int i = t - 64; i < 2560; i += 960) c2wS[i] = c2w[i];
    }
    __syncthreads();

    // bitonic-128 sort (ascending) of the 30 selected rows only
    for (int k = wv; k < 30; k += 16) {
        const float* fr = F + selI[k] * 100;
        float v0 = fr[lane];
        float v1 = (lane < 33) ? fr[64 + lane] : INFINITY;
        for (int kk = 2; kk <= 128; kk <<= 1) {
            for (int jj = kk >> 1; jj > 0; jj >>= 1) {
                if (jj == 64) {
                    const float lo = fminf(v0, v1), hi = fmaxf(v0, v1);
                    v0 = lo; v1 = hi;
                } else {
                    const float p0 = __shfl_xor(v0, jj, 64);
                    const float p1 = __shfl_xor(v1, jj, 64);
                    const bool up   = ((lane & jj) == 0);
                    const bool asc0 = (kk == 128) ? true : ((lane & kk) == 0);
                    const bool asc1 = (kk == 128) ? true : (((64 + lane) & kk) == 0);
                    v0 = (up == asc0) ? fminf(v0, p0) : fmaxf(v0, p0);
                    v1 = (up == asc1) ? fminf(v1, p1) : fmaxf(v1, p1);
                }
            }
        }
        S30[k * 100 + lane] = v0;
        if (lane < 33) S30[k * 100 + 64 + lane] = v1;
    }
    __syncthreads();

    // conv1 (16 ch, kernel 97, stride 97) + relu
    if (t < 480) {
        const int k = t >> 4, c = t & 15;
        const float* row  = S30 + k * 100;
        const float* wrow = c1wS + c * 97;
        float acc = c1b[c];
        for (int d = 0; d < 97; ++d) acc = fmaf(row[d], wrow[d], acc);
        L1[k * 16 + c] = fmaxf(acc, 0.f);
    }
    __syncthreads();
    if (t < 240) {
        const int c = t / 15, tt = t % 15;
        Q[c * 15 + tt] = fmaxf(L1[(2 * tt) * 16 + c], L1[(2 * tt + 1) * 16 + c]);
    }
    __syncthreads();
    if (t < 352) {
        const int o = t / 11, tt = t % 11;
        const float* wo = c2wS + o * 80;
        float acc = c2b[o];
        #pragma unroll
        for (int c = 0; c < 16; ++c)
            #pragma unroll
            for (int jj = 0; jj < 5; ++jj)
                acc = fmaf(Q[c * 15 + tt + jj], wo[c * 5 + jj], acc);
        Rr[o * 11 + tt] = fmaxf(acc, 0.f);
    }
    __syncthreads();
    if (t < 128) {
        float acc = f1b[t];
        const float* wr = f1w + t * 352;
        for (int i = 0; i < 352; ++i) acc = fmaf(Rr[i], wr[i], acc);
        Ff[t] = fmaxf(acc, 0.f);
    }
    __syncthreads();
    if (t < 64) {
        float acc = Ff[lane] * f2w[lane] + Ff[lane + 64] * f2w[lane + 64];
        #pragma unroll
        for (int off = 1; off <= 32; off <<= 1) acc += __shfl_xor(acc, off, 64);
        if (lane == 0) out[g] = acc + f2b[0];
    }
}

extern "C" void kernel_launch(void* const* d_in, const int* in_sizes, int n_in,
                              void* d_out, int out_size, void* d_ws, size_t ws_size,
                              hipStream_t stream)
{
    const int*   feats    = (const int*)d_in[0];
    const int*   node_id  = (const int*)d_in[1];
    const int*   edge_id  = (const int*)d_in[2];
    const int*   src      = (const int*)d_in[3];
    const int*   dst      = (const int*)d_in[4];
    const float* ndata    = (const float*)d_in[5];
    const float* edata    = (const float*)d_in[6];
    const float* node_emb = (const float*)d_in[7];
    const float* W0 = (const float*)d_in[8];
    const float* b0 = (const float*)d_in[9];
    const float* W1 = (const float*)d_in[10];
    const float* b1 = (const float*)d_in[11];
    const float* W2 = (const float*)d_in[12];
    const float* b2 = (const float*)d_in[13];
    const float* W3 = (const float*)d_in[14];
    const float* b3 = (const float*)d_in[15];
    const float* c1w = (const float*)d_in[16];
    const float* c1b = (const float*)d_in[17];
    const float* c2w = (const float*)d_in[18];
    const float* c2b = (const float*)d_in[19];
    const float* f1w = (const float*)d_in[20];
    const float* f1b = (const float*)d_in[21];
    const float* f2w = (const float*)d_in[22];
    const float* f2b = (const float*)d_in[23];

    (void)hipFuncSetAttribute((const void*)dgcnn_fused,
                              hipFuncAttributeMaxDynamicSharedMemorySize, A_TOTAL);

    dgcnn_fused<<<NGRAPH, 1024, A_TOTAL, stream>>>(feats, node_id, edge_id, src, dst,
                                                   ndata, edata, node_emb,
                                                   W0, b0, W1, b1, W2, b2, W3, b3,
                                                   c1w, c1b, c2w, c2b,
                                                   f1w, f1b, f2w, f2b,
                                                   (float*)d_out);
}

// Round 4
// 390.160 us; speedup vs baseline: 3.1413x; 1.0674x over previous
//
#include <hip/hip_runtime.h>
#include <math.h>

#define NPG    256
#define EPG    4096
#define NGRAPH 1024
#define NATTR  100000

// global scratch (static device arrays; ws_size not relied upon)
__device__ float g_F[(size_t)NGRAPH * NPG * 100];      // per-node 97-dim features, stride 100
__device__ uint2 g_edges[(size_t)NGRAPH * EPG + 8];    // dst-sorted {w_bits, src}, +pad for prefetch

// ---------------- LDS layout (bytes), total 79,520 <= 80 KiB -> 2 blocks/CU ----------------
#define A_BUFA   0        // float[256*36] 36864 : ping buffer (h*ns / head scratch / phaseE deg)
#define A_BUFB   36864    // float[256*36] 36864 : pong buffer (y staging / phaseE ewRaw)
#define A_ROWS   73728    // int[257] 1056
#define A_NS     74784    // float[256]
#define A_ND     75808    // float[256]
#define A_BS     76832    // float[97] -> 512
#define A_KEYS   77344    // float[256]
#define A_Y4     78368    // float[256]
#define A_SEL    79392    // int[32]
#define A_TOTAL  79520

// phase-E scratch
#define E_DEGI   0        // in BUFA: int[256]
#define E_DEGO   1024     // int[256]
#define E_CUR    2048     // int[256]
// ewRaw: float[4096] in BUFB

// head scratch (inside BUFA/BUFB region)
#define H_S30    0        // float[30][100] 12000
#define H_C1W    12000    // float[1552] 6208
#define H_C2W    18208    // float[2560] 10240  (ends 28448)
#define H_L1     28448    // float[480] 1920
#define H_Q      30368    // float[240] 960
#define H_RR     31328    // float[352] 1408
#define H_FF     32736    // float[128] 512     (ends 33248 < 36864)

// aggregate 32-dim Y (stride 36) over dst-sorted global edges (1-deep prefetch),
// tanh-activate -> write h to global F row, h*ns to Hout (LDS), update keys.
__device__ __forceinline__ void aggregate32(const uint2* __restrict__ gE,
                                            const int* rowS, const float* Y,
                                            const float* ns, const float* nd,
                                            const float* Bs, int boff,
                                            float* Hout, float* keys,
                                            float* __restrict__ gFg, int t)
{
    #pragma unroll
    for (int r = 0; r < 2; ++r) {
        const int n = r * 128 + (t >> 3);
        const int q = t & 7;
        const int rs = rowS[n], re = rowS[n + 1];
        double a0 = 0.0, a1 = 0.0, a2 = 0.0, a3 = 0.0;
        uint2 e0 = gE[rs];
        float4 y0 = *(const float4*)(Y + e0.y * 36 + q * 4);
        for (int e = rs; e < re; ++e) {
            const uint2 e1 = gE[e + 1];                       // padded
            const float4 y1 = *(const float4*)(Y + e1.y * 36 + q * 4);
            const double w = (double)__uint_as_float(e0.x);
            a0 += (double)y0.x * w;
            a1 += (double)y0.y * w;
            a2 += (double)y0.z * w;
            a3 += (double)y0.w * w;
            e0 = e1; y0 = y1;
        }
        const double sc = (double)nd[n];
        float4 hv;
        hv.x = tanhf((float)(a0 * sc) + Bs[boff + q * 4 + 0]);
        hv.y = tanhf((float)(a1 * sc) + Bs[boff + q * 4 + 1]);
        hv.z = tanhf((float)(a2 * sc) + Bs[boff + q * 4 + 2]);
        hv.w = tanhf((float)(a3 * sc) + Bs[boff + q * 4 + 3]);
        *(float4*)(gFg + (size_t)n * 100 + boff + q * 4) = hv;
        const float s2 = ns[n];
        float4 o; o.x = hv.x * s2; o.y = hv.y * s2; o.z = hv.z * s2; o.w = hv.w * s2;
        *(float4*)(Hout + n * 36 + q * 4) = o;
        float m = fmaxf(fmaxf(hv.x, hv.y), fmaxf(hv.z, hv.w));
        m = fmaxf(m, __shfl_xor(m, 1, 64));
        m = fmaxf(m, __shfl_xor(m, 2, 64));
        m = fmaxf(m, __shfl_xor(m, 4, 64));
        if (q == 0) keys[n] = fmaxf(keys[n], m);
    }
}

extern "C" __global__ void __launch_bounds__(1024, 8)
dgcnn_fused(const int* __restrict__ feats, const int* __restrict__ node_id,
            const int* __restrict__ edge_id, const int* __restrict__ src,
            const int* __restrict__ dst,
            const float* __restrict__ ndata, const float* __restrict__ edata,
            const float* __restrict__ node_emb,
            const float* __restrict__ W0, const float* __restrict__ b0,
            const float* __restrict__ W1, const float* __restrict__ b1,
            const float* __restrict__ W2, const float* __restrict__ b2,
            const float* __restrict__ W3, const float* __restrict__ b3,
            const float* __restrict__ c1w, const float* __restrict__ c1b,
            const float* __restrict__ c2w, const float* __restrict__ c2b,
            const float* __restrict__ f1w, const float* __restrict__ f1b,
            const float* __restrict__ f2w, const float* __restrict__ f2b,
            float* __restrict__ out)
{
    extern __shared__ char smem[];
    float* BufA = (float*)(smem + A_BUFA);
    float* BufB = (float*)(smem + A_BUFB);
    int*   rowS = (int*)(smem + A_ROWS);
    float* ns   = (float*)(smem + A_NS);
    float* nd   = (float*)(smem + A_ND);
    float* Bs   = (float*)(smem + A_BS);
    float* keys = (float*)(smem + A_KEYS);
    float* y4   = (float*)(smem + A_Y4);
    int*   selI = (int*)(smem + A_SEL);

    const int g = blockIdx.x, t = threadIdx.x;
    const int lane = t & 63, wv = t >> 6;
    float* gFg = g_F + (size_t)g * NPG * 100;
    uint2* gE  = g_edges + (size_t)g * EPG;

    // ---------------- phase E ----------------
    int* degI = (int*)((char*)BufA + E_DEGI);
    int* degO = (int*)((char*)BufA + E_DEGO);
    int* cur  = (int*)((char*)BufA + E_CUR);
    float* ewRaw = BufB;

    if (t < NPG) { degI[t] = 0; degO[t] = 0; keys[t] = -INFINITY; }
    if (t < 97) Bs[t] = (t < 32) ? b0[t] : (t < 64) ? b1[t - 32]
                       : (t < 96) ? b2[t - 64] : b3[0];
    __syncthreads();
    for (int e = t; e < EPG; e += 1024) {
        const int ge = g * EPG + e;
        const int s = src[ge] - g * NPG;
        const int d = dst[ge] - g * NPG;
        ewRaw[e] = edata[edge_id[ge]];
        atomicAdd(&degO[s], 1);
        atomicAdd(&degI[d], 1);
    }
    __syncthreads();
    // single-wave shuffle prefix scan of degI -> rowS
    if (t < 64) {
        const int d0 = degI[4 * t], d1 = degI[4 * t + 1],
                  d2 = degI[4 * t + 2], d3 = degI[4 * t + 3];
        const int p1 = d0, p2 = p1 + d1, p3 = p2 + d2, p4 = p3 + d3;
        int s = p4;
        #pragma unroll
        for (int off = 1; off <= 32; off <<= 1) {
            const int o = __shfl_up(s, off, 64);
            if (lane >= off) s += o;
        }
        const int excl = s - p4;
        rowS[4 * t + 1] = excl + p1;
        rowS[4 * t + 2] = excl + p2;
        rowS[4 * t + 3] = excl + p3;
        rowS[4 * t + 4] = excl + p4;
        if (t == 0) rowS[0] = 0;
    }
    __syncthreads();
    if (t < NPG) {
        ns[t] = (float)(1.0 / sqrt((double)(degO[t] > 0 ? degO[t] : 1)));
        nd[t] = (float)(1.0 / sqrt((double)(degI[t] > 0 ? degI[t] : 1)));
        cur[t] = rowS[t];
    }
    __syncthreads();
    for (int e = t; e < EPG; e += 1024) {
        const int ge = g * EPG + e;
        const int s = src[ge] - g * NPG;
        const int d = dst[ge] - g * NPG;
        const int pos = atomicAdd(&cur[d], 1);
        gE[pos] = make_uint2(__float_as_uint(ewRaw[e]), (uint)s);
    }
    __syncthreads();

    const int j = t & 31, nb = t >> 5;

    // ---------------- Layer 1: y = (x*ns) @ W0 via 4 input chunks (staged in BufB) ----------------
    {
        float acc[8] = {0.f, 0.f, 0.f, 0.f, 0.f, 0.f, 0.f, 0.f};
        for (int c = 0; c < 4; ++c) {
            for (int i = t; i < 2048; i += 1024) {
                const int n = i >> 3, q = i & 7;
                const int gn = g * NPG + n;
                const int nidn = node_id[gn];
                const int j0 = c * 32 + q * 4;
                float4 v;
                if (j0 < 64)      v = *(const float4*)(ndata    + (size_t)nidn * 64 + j0);
                else if (j0 < 96) v = *(const float4*)(node_emb + (size_t)feats[gn] * 32 + (j0 - 64));
                else              v = *(const float4*)(node_emb + (size_t)(NATTR + nidn) * 32 + (j0 - 96));
                const float sc = ns[n];
                float4 o; o.x = v.x * sc; o.y = v.y * sc; o.z = v.z * sc; o.w = v.w * sc;
                *(float4*)(BufB + n * 36 + q * 4) = o;
            }
            __syncthreads();
            float wc[32];
            #pragma unroll
            for (int d = 0; d < 32; ++d) wc[d] = W0[(c * 32 + d) * 32 + j];
            #pragma unroll
            for (int i2 = 0; i2 < 8; ++i2) {
                const int n = nb * 8 + i2;
                const float4* ar = (const float4*)(BufB + n * 36);
                float a = acc[i2];
                #pragma unroll
                for (int d8 = 0; d8 < 8; ++d8) {
                    const float4 av = ar[d8];
                    a = fmaf(av.x, wc[4 * d8 + 0], a);
                    a = fmaf(av.y, wc[4 * d8 + 1], a);
                    a = fmaf(av.z, wc[4 * d8 + 2], a);
                    a = fmaf(av.w, wc[4 * d8 + 3], a);
                }
                acc[i2] = a;
            }
            __syncthreads();
        }
        #pragma unroll
        for (int i2 = 0; i2 < 8; ++i2) BufB[(nb * 8 + i2) * 36 + j] = acc[i2];
        __syncthreads();
        aggregate32(gE, rowS, BufB, ns, nd, Bs, 0, BufA, keys, gFg, t);
        __syncthreads();
    }

    // ---------------- Layers 2, 3: transform BufA -> BufB, aggregate BufB -> BufA ----------------
    for (int L = 0; L < 2; ++L) {
        const float* WL = L ? W2 : W1;
        float wc[32];
        #pragma unroll
        for (int d = 0; d < 32; ++d) wc[d] = WL[d * 32 + j];
        float acc[8];
        #pragma unroll
        for (int i2 = 0; i2 < 8; ++i2) {
            const int n = nb * 8 + i2;
            const float4* fr = (const float4*)(BufA + n * 36);
            float a = 0.f;
            #pragma unroll
            for (int d8 = 0; d8 < 8; ++d8) {
                const float4 av = fr[d8];
                a = fmaf(av.x, wc[4 * d8 + 0], a);
                a = fmaf(av.y, wc[4 * d8 + 1], a);
                a = fmaf(av.z, wc[4 * d8 + 2], a);
                a = fmaf(av.w, wc[4 * d8 + 3], a);
            }
            acc[i2] = a;
        }
        __syncthreads();                   // BufA reads done before overwrite in aggregate
        #pragma unroll
        for (int i2 = 0; i2 < 8; ++i2) BufB[(nb * 8 + i2) * 36 + j] = acc[i2];
        __syncthreads();
        aggregate32(gE, rowS, BufB, ns, nd, Bs, 32 + L * 32, BufA, keys, gFg, t);
        __syncthreads();
    }

    // ---------------- Layer 4: y4 = (h3*ns) @ W3, scalar aggregate ----------------
    if (t < NPG) {
        const float4* fr = (const float4*)(BufA + t * 36);
        float a = 0.f;
        #pragma unroll
        for (int d8 = 0; d8 < 8; ++d8) {
            const float4 h = fr[d8];
            a = fmaf(h.x, W3[4 * d8 + 0], a);
            a = fmaf(h.y, W3[4 * d8 + 1], a);
            a = fmaf(h.z, W3[4 * d8 + 2], a);
            a = fmaf(h.w, W3[4 * d8 + 3], a);
        }
        y4[t] = a;
    }
    __syncthreads();
    {
        const int n = t >> 2, p = t & 3;
        const int rs = rowS[n], re = rowS[n + 1];
        double a = 0.0;
        for (int e = rs + p; e < re; e += 4) {
            const uint2 ed = gE[e];
            a += (double)__uint_as_float(ed.x) * (double)y4[ed.y];
        }
        a += __shfl_xor(a, 1, 64);
        a += __shfl_xor(a, 2, 64);
        if (p == 0) {
            const float h = tanhf((float)(a * (double)nd[n]) + Bs[96]);
            gFg[(size_t)n * 100 + 96] = h;
            keys[n] = fmaxf(keys[n], h);
        }
    }
    __syncthreads();

    // ---------------- head ----------------
    char*  HB   = (char*)BufA;
    float* S30  = (float*)(HB + H_S30);
    float* c1wS = (float*)(HB + H_C1W);
    float* c2wS = (float*)(HB + H_C2W);
    float* L1   = (float*)(HB + H_L1);
    float* Q    = (float*)(HB + H_Q);
    float* Rr   = (float*)(HB + H_RR);
    float* Ff   = (float*)(HB + H_FF);

    if (t < 64) {
        // wave 0: top-30, jax.lax.top_k tie semantics (desc value, asc index)
        float kv[4]; int ki[4];
        #pragma unroll
        for (int r = 0; r < 4; ++r) { ki[r] = lane * 4 + r; kv[r] = keys[lane * 4 + r]; }
        for (int it = 0; it < 30; ++it) {
            float bv = kv[0]; int bi = ki[0];
            #pragma unroll
            for (int r = 1; r < 4; ++r)
                if (kv[r] > bv || (kv[r] == bv && ki[r] < bi)) { bv = kv[r]; bi = ki[r]; }
            #pragma unroll
            for (int off = 1; off <= 32; off <<= 1) {
                const float ov = __shfl_xor(bv, off, 64);
                const int   oi = __shfl_xor(bi, off, 64);
                if (ov > bv || (ov == bv && oi < bi)) { bv = ov; bi = oi; }
            }
            if (lane == 0) selI[it] = bi;
            if ((bi >> 2) == lane) kv[bi & 3] = -INFINITY;
        }
    } else {
        for (int i = t - 64; i < 1552; i += 960) c1wS[i] = c1w[i];
        for (int i = t - 64; i < 2560; i += 960) c2wS[i] = c2w[i];
    }
    __syncthreads();

    // bitonic-128 sort (ascending) of the 30 selected rows (from global F)
    for (int k = wv; k < 30; k += 16) {
        const float* fr = gFg + (size_t)selI[k] * 100;
        float v0 = fr[lane];
        float v1 = (lane < 33) ? fr[64 + lane] : INFINITY;
        for (int kk = 2; kk <= 128; kk <<= 1) {
            for (int jj = kk >> 1; jj > 0; jj >>= 1) {
                if (jj == 64) {
                    const float lo = fminf(v0, v1), hi = fmaxf(v0, v1);
                    v0 = lo; v1 = hi;
                } else {
                    const float p0 = __shfl_xor(v0, jj, 64);
                    const float p1 = __shfl_xor(v1, jj, 64);
                    const bool up   = ((lane & jj) == 0);
                    const bool asc0 = (kk == 128) ? true : ((lane & kk) == 0);
                    const bool asc1 = (kk == 128) ? true : (((64 + lane) & kk) == 0);
                    v0 = (up == asc0) ? fminf(v0, p0) : fmaxf(v0, p0);
                    v1 = (up == asc1) ? fminf(v1, p1) : fmaxf(v1, p1);
                }
            }
        }
        S30[k * 100 + lane] = v0;
        if (lane < 33) S30[k * 100 + 64 + lane] = v1;
    }
    __syncthreads();

    // conv1 (16 ch, kernel 97, stride 97) + relu
    if (t < 480) {
        const int k = t >> 4, c = t & 15;
        const float* row  = S30 + k * 100;
        const float* wrow = c1wS + c * 97;
        float acc = c1b[c];
        for (int d = 0; d < 97; ++d) acc = fmaf(row[d], wrow[d], acc);
        L1[k * 16 + c] = fmaxf(acc, 0.f);
    }
    __syncthreads();
    if (t < 240) {
        const int c = t / 15, tt = t % 15;
        Q[c * 15 + tt] = fmaxf(L1[(2 * tt) * 16 + c], L1[(2 * tt + 1) * 16 + c]);
    }
    __syncthreads();
    if (t < 352) {
        const int o = t / 11, tt = t % 11;
        const float* wo = c2wS + o * 80;
        float acc = c2b[o];
        #pragma unroll
        for (int c = 0; c < 16; ++c)
            #pragma unroll
            for (int jj = 0; jj < 5; ++jj)
                acc = fmaf(Q[c * 15 + tt + jj], wo[c * 5 + jj], acc);
        Rr[o * 11 + tt] = fmaxf(acc, 0.f);
    }
    __syncthreads();
    if (t < 128) {
        float acc = f1b[t];
        const float* wr = f1w + t * 352;
        for (int i = 0; i < 352; ++i) acc = fmaf(Rr[i], wr[i], acc);
        Ff[t] = fmaxf(acc, 0.f);
    }
    __syncthreads();
    if (t < 64) {
        float acc = Ff[lane] * f2w[lane] + Ff[lane + 64] * f2w[lane + 64];
        #pragma unroll
        for (int off = 1; off <= 32; off <<= 1) acc += __shfl_xor(acc, off, 64);
        if (lane == 0) out[g] = acc + f2b[0];
    }
}

extern "C" void kernel_launch(void* const* d_in, const int* in_sizes, int n_in,
                              void* d_out, int out_size, void* d_ws, size_t ws_size,
                              hipStream_t stream)
{
    const int*   feats    = (const int*)d_in[0];
    const int*   node_id  = (const int*)d_in[1];
    const int*   edge_id  = (const int*)d_in[2];
    const int*   src      = (const int*)d_in[3];
    const int*   dst      = (const int*)d_in[4];
    const float* ndata    = (const float*)d_in[5];
    const float* edata    = (const float*)d_in[6];
    const float* node_emb = (const float*)d_in[7];
    const float* W0 = (const float*)d_in[8];
    const float* b0 = (const float*)d_in[9];
    const float* W1 = (const float*)d_in[10];
    const float* b1 = (const float*)d_in[11];
    const float* W2 = (const float*)d_in[12];
    const float* b2 = (const float*)d_in[13];
    const float* W3 = (const float*)d_in[14];
    const float* b3 = (const float*)d_in[15];
    const float* c1w = (const float*)d_in[16];
    const float* c1b = (const float*)d_in[17];
    const float* c2w = (const float*)d_in[18];
    const float* c2b = (const float*)d_in[19];
    const float* f1w = (const float*)d_in[20];
    const float* f1b = (const float*)d_in[21];
    const float* f2w = (const float*)d_in[22];
    const float* f2b = (const float*)d_in[23];

    (void)hipFuncSetAttribute((const void*)dgcnn_fused,
                              hipFuncAttributeMaxDynamicSharedMemorySize, A_TOTAL);

    dgcnn_fused<<<NGRAPH, 1024, A_TOTAL, stream>>>(feats, node_id, edge_id, src, dst,
                                                   ndata, edata, node_emb,
                                                   W0, b0, W1, b1, W2, b2, W3, b3,
                                                   c1w, c1b, c2w, c2b,
                                                   f1w, f1b, f2w, f2b,
                                                   (float*)d_out);
}

// Round 5
// 370.038 us; speedup vs baseline: 3.3121x; 1.0544x over previous
//
#include <hip/hip_runtime.h>
#include <math.h>

#define NPG    256
#define EPG    4096
#define NGRAPH 1024
#define NATTR  100000

// per-node 97-dim feature rows (stride 100), ~105 MB global scratch
__device__ float g_F[(size_t)NGRAPH * NPG * 100];

// ---------------- LDS layout (bytes), total 76,000 <= 80 KiB -> 2 blocks/CU ----------------
#define A_Y      0        // float[256*36] 36864 : staging / transformed features (union: phase-E, head)
#define A_E      36864    // uint2[4100] 32800->32832 : dst-sorted edges {w_bits, src}
#define A_ROWS   69696    // int[257] 1056
#define A_NS     70752    // float[256]
#define A_ND     71776    // float[256]
#define A_BS     72800    // float[97] -> 512
#define A_KEYS   73312    // float[256]
#define A_Y4     74336    // float[256]
#define A_SEL    75360    // int[32] -> 128
#define A_ORD    75488    // ushort[256] 512
#define A_TOTAL  76000

// phase-E scratch inside Y region
#define E_EWRAW  0        // float[4096] 16384
#define E_RAWSD  16384    // uint[4096] 16384
#define E_DEGI   32768    // int[256]
#define E_DEGO   33792    // int[256]
#define E_CUR    34816    // int[256]  (end 35840 <= 36864)

// head scratch inside Y region
#define H_S30    0        // float[30][100] 12000
#define H_C1W    12000    // float[1552] 6208
#define H_C2W    18208    // float[2560] 10240
#define H_L1     28448    // float[480]
#define H_Q      30368    // float[240]
#define H_RR     31328    // float[352]
#define H_FF     32736    // float[128]  (end 33248 <= 36864)

// aggregate 32-dim Y (stride 36) over dst-sorted LDS edges, 2-deep pipeline,
// degree-sorted node order; tanh -> write h to gF, update keys.
__device__ __forceinline__ void aggregate32(const uint2* sE, const int* rowS,
                                            const ushort* ord, const float* Y,
                                            const float* nd, const float* Bs, int boff,
                                            float* keys, float* __restrict__ gFg, int t)
{
    #pragma unroll
    for (int r = 0; r < 2; ++r) {
        const int n = ord[r * 128 + (t >> 3)];
        const int q = t & 7;
        const int rs = rowS[n], re = rowS[n + 1];
        double a0 = 0.0, a1 = 0.0, a2 = 0.0, a3 = 0.0;
        uint2 e0 = sE[rs];
        uint2 e1 = sE[rs + 1];
        float4 y0 = *(const float4*)(Y + e0.y * 36 + q * 4);
        for (int e = rs; e < re; ++e) {
            const float4 y1 = *(const float4*)(Y + e1.y * 36 + q * 4);
            const uint2 e2 = sE[e + 2];                  // pad-safe
            const double w = (double)__uint_as_float(e0.x);
            a0 += (double)y0.x * w;
            a1 += (double)y0.y * w;
            a2 += (double)y0.z * w;
            a3 += (double)y0.w * w;
            e0 = e1; e1 = e2; y0 = y1;
        }
        const double sc = (double)nd[n];
        float4 hv;
        hv.x = tanhf((float)(a0 * sc) + Bs[boff + q * 4 + 0]);
        hv.y = tanhf((float)(a1 * sc) + Bs[boff + q * 4 + 1]);
        hv.z = tanhf((float)(a2 * sc) + Bs[boff + q * 4 + 2]);
        hv.w = tanhf((float)(a3 * sc) + Bs[boff + q * 4 + 3]);
        *(float4*)(gFg + (size_t)n * 100 + boff + q * 4) = hv;
        float m = fmaxf(fmaxf(hv.x, hv.y), fmaxf(hv.z, hv.w));
        m = fmaxf(m, __shfl_xor(m, 1, 64));
        m = fmaxf(m, __shfl_xor(m, 2, 64));
        m = fmaxf(m, __shfl_xor(m, 4, 64));
        if (q == 0) keys[n] = fmaxf(keys[n], m);
    }
}

extern "C" __global__ void __launch_bounds__(1024, 8)
dgcnn_fused(const int* __restrict__ feats, const int* __restrict__ node_id,
            const int* __restrict__ edge_id, const int* __restrict__ src,
            const int* __restrict__ dst,
            const float* __restrict__ ndata, const float* __restrict__ edata,
            const float* __restrict__ node_emb,
            const float* __restrict__ W0, const float* __restrict__ b0,
            const float* __restrict__ W1, const float* __restrict__ b1,
            const float* __restrict__ W2, const float* __restrict__ b2,
            const float* __restrict__ W3, const float* __restrict__ b3,
            const float* __restrict__ c1w, const float* __restrict__ c1b,
            const float* __restrict__ c2w, const float* __restrict__ c2b,
            const float* __restrict__ f1w, const float* __restrict__ f1b,
            const float* __restrict__ f2w, const float* __restrict__ f2b,
            float* __restrict__ out)
{
    extern __shared__ char smem[];
    float*  Y    = (float*)(smem + A_Y);
    uint2*  sE   = (uint2*)(smem + A_E);
    int*    rowS = (int*)(smem + A_ROWS);
    float*  ns   = (float*)(smem + A_NS);
    float*  nd   = (float*)(smem + A_ND);
    float*  Bs   = (float*)(smem + A_BS);
    float*  keys = (float*)(smem + A_KEYS);
    float*  y4   = (float*)(smem + A_Y4);
    int*    selI = (int*)(smem + A_SEL);
    ushort* ord  = (ushort*)(smem + A_ORD);

    const int g = blockIdx.x, t = threadIdx.x;
    const int lane = t & 63, wv = t >> 6;
    float* gFg = g_F + (size_t)g * NPG * 100;

    // ---------------- phase E ----------------
    float* ewRaw = (float*)((char*)Y + E_EWRAW);
    uint*  rawSD = (uint*)((char*)Y + E_RAWSD);
    int*   degI  = (int*)((char*)Y + E_DEGI);
    int*   degO  = (int*)((char*)Y + E_DEGO);
    int*   cur   = (int*)((char*)Y + E_CUR);

    if (t < NPG) { degI[t] = 0; degO[t] = 0; keys[t] = -INFINITY; }
    if (t < 97) Bs[t] = (t < 32) ? b0[t] : (t < 64) ? b1[t - 32]
                       : (t < 96) ? b2[t - 64] : b3[0];
    if (t < 4) sE[4096 + t] = make_uint2(0u, 0u);        // pipeline sentinels
    __syncthreads();
    for (int e = t; e < EPG; e += 1024) {
        const int ge = g * EPG + e;
        const int s = src[ge] - g * NPG;
        const int d = dst[ge] - g * NPG;
        rawSD[e] = (uint)s | ((uint)d << 16);
        ewRaw[e] = edata[edge_id[ge]];
        atomicAdd(&degO[s], 1);
        atomicAdd(&degI[d], 1);
    }
    __syncthreads();
    // single-wave shuffle prefix scan of degI -> rowS
    if (t < 64) {
        const int d0 = degI[4 * t], d1 = degI[4 * t + 1],
                  d2 = degI[4 * t + 2], d3 = degI[4 * t + 3];
        const int p1 = d0, p2 = p1 + d1, p3 = p2 + d2, p4 = p3 + d3;
        int s = p4;
        #pragma unroll
        for (int off = 1; off <= 32; off <<= 1) {
            const int o = __shfl_up(s, off, 64);
            if (lane >= off) s += o;
        }
        const int excl = s - p4;
        rowS[4 * t + 1] = excl + p1;
        rowS[4 * t + 2] = excl + p2;
        rowS[4 * t + 3] = excl + p3;
        rowS[4 * t + 4] = excl + p4;
        if (t == 0) rowS[0] = 0;
    }
    __syncthreads();
    if (t < NPG) {
        ns[t] = (float)(1.0 / sqrt((double)(degO[t] > 0 ? degO[t] : 1)));
        nd[t] = (float)(1.0 / sqrt((double)(degI[t] > 0 ? degI[t] : 1)));
        cur[t] = rowS[t];
    }
    __syncthreads();
    for (int e = t; e < EPG; e += 1024) {
        const uint sd = rawSD[e];
        const int d = (int)(sd >> 16), s = (int)(sd & 0xffffu);
        const int pos = atomicAdd(&cur[d], 1);
        sE[pos] = make_uint2(__float_as_uint(ewRaw[e]), (uint)s);
    }
    __syncthreads();
    // degree-sort nodes (counting sort by clamped in-degree) -> ord
    if (t < NPG) degO[t] = 0;                            // hist
    __syncthreads();
    if (t < NPG) atomicAdd(&degO[min(degI[t], 255)], 1);
    __syncthreads();
    if (t < 64) {                                        // exclusive prefix of hist -> cur
        const int d0 = degO[4 * t], d1 = degO[4 * t + 1],
                  d2 = degO[4 * t + 2], d3 = degO[4 * t + 3];
        const int p1 = d0, p2 = p1 + d1, p3 = p2 + d2, p4 = p3 + d3;
        int s = p4;
        #pragma unroll
        for (int off = 1; off <= 32; off <<= 1) {
            const int o = __shfl_up(s, off, 64);
            if (lane >= off) s += o;
        }
        const int excl = s - p4;
        cur[4 * t]     = excl;
        cur[4 * t + 1] = excl + p1;
        cur[4 * t + 2] = excl + p2;
        cur[4 * t + 3] = excl + p3;
    }
    __syncthreads();
    if (t < NPG) {
        const int pos = atomicAdd(&cur[min(degI[t], 255)], 1);
        ord[pos] = (ushort)t;
    }
    __syncthreads();

    const int j = t & 31, nb = t >> 5;

    // ---------------- Layer 1: y = (x*ns) @ W0 via 4 input chunks (staged in Y, in-place) ----------------
    {
        float acc[8] = {0.f, 0.f, 0.f, 0.f, 0.f, 0.f, 0.f, 0.f};
        for (int c = 0; c < 4; ++c) {
            for (int i = t; i < 2048; i += 1024) {
                const int n = i >> 3, q = i & 7;
                const int gn = g * NPG + n;
                const int nidn = node_id[gn];
                const int j0 = c * 32 + q * 4;
                float4 v;
                if (j0 < 64)      v = *(const float4*)(ndata    + (size_t)nidn * 64 + j0);
                else if (j0 < 96) v = *(const float4*)(node_emb + (size_t)feats[gn] * 32 + (j0 - 64));
                else              v = *(const float4*)(node_emb + (size_t)(NATTR + nidn) * 32 + (j0 - 96));
                const float sc = ns[n];
                float4 o; o.x = v.x * sc; o.y = v.y * sc; o.z = v.z * sc; o.w = v.w * sc;
                *(float4*)(Y + n * 36 + q * 4) = o;
            }
            __syncthreads();
            float wc[32];
            #pragma unroll
            for (int d = 0; d < 32; ++d) wc[d] = W0[(c * 32 + d) * 32 + j];
            #pragma unroll
            for (int i2 = 0; i2 < 8; ++i2) {
                const int n = nb * 8 + i2;
                const float4* ar = (const float4*)(Y + n * 36);
                float a = acc[i2];
                #pragma unroll
                for (int d8 = 0; d8 < 8; ++d8) {
                    const float4 av = ar[d8];
                    a = fmaf(av.x, wc[4 * d8 + 0], a);
                    a = fmaf(av.y, wc[4 * d8 + 1], a);
                    a = fmaf(av.z, wc[4 * d8 + 2], a);
                    a = fmaf(av.w, wc[4 * d8 + 3], a);
                }
                acc[i2] = a;
            }
            __syncthreads();
        }
        #pragma unroll
        for (int i2 = 0; i2 < 8; ++i2) Y[(nb * 8 + i2) * 36 + j] = acc[i2];
        __syncthreads();
        aggregate32(sE, rowS, ord, Y, nd, Bs, 0, keys, gFg, t);
        __syncthreads();
    }

    // ---------------- Layers 2, 3: y = ns * (h @ W), h read from gF ----------------
    for (int L = 0; L < 2; ++L) {
        const float* WL = L ? W2 : W1;
        const int pb = L ? 32 : 0;
        float wc[32];
        #pragma unroll
        for (int d = 0; d < 32; ++d) wc[d] = WL[d * 32 + j];
        float acc[8];
        #pragma unroll
        for (int i2 = 0; i2 < 8; ++i2) {
            const int n = nb * 8 + i2;
            const float4* fr = (const float4*)(gFg + (size_t)n * 100 + pb);
            float a = 0.f;
            #pragma unroll
            for (int d8 = 0; d8 < 8; ++d8) {
                const float4 av = fr[d8];
                a = fmaf(av.x, wc[4 * d8 + 0], a);
                a = fmaf(av.y, wc[4 * d8 + 1], a);
                a = fmaf(av.z, wc[4 * d8 + 2], a);
                a = fmaf(av.w, wc[4 * d8 + 3], a);
            }
            acc[i2] = a * ns[n];
        }
        __syncthreads();                 // Y free (previous aggregate done reading)
        #pragma unroll
        for (int i2 = 0; i2 < 8; ++i2) Y[(nb * 8 + i2) * 36 + j] = acc[i2];
        __syncthreads();
        aggregate32(sE, rowS, ord, Y, nd, Bs, 32 + L * 32, keys, gFg, t);
        __syncthreads();
    }

    // ---------------- Layer 4: y4 = ns * (h3 @ W3), scalar aggregate ----------------
    if (t < NPG) {
        const float4* fr = (const float4*)(gFg + (size_t)t * 100 + 64);
        float a = 0.f;
        #pragma unroll
        for (int d8 = 0; d8 < 8; ++d8) {
            const float4 h = fr[d8];
            a = fmaf(h.x, W3[4 * d8 + 0], a);
            a = fmaf(h.y, W3[4 * d8 + 1], a);
            a = fmaf(h.z, W3[4 * d8 + 2], a);
            a = fmaf(h.w, W3[4 * d8 + 3], a);
        }
        y4[t] = a * ns[t];
    }
    __syncthreads();
    {
        const int n = ord[t >> 2], p = t & 3;
        const int rs = rowS[n], re = rowS[n + 1];
        double a = 0.0;
        for (int e = rs + p; e < re; e += 4) {
            const uint2 ed = sE[e];
            a += (double)__uint_as_float(ed.x) * (double)y4[ed.y];
        }
        a += __shfl_xor(a, 1, 64);
        a += __shfl_xor(a, 2, 64);
        if (p == 0) {
            const float h = tanhf((float)(a * (double)nd[n]) + Bs[96]);
            gFg[(size_t)n * 100 + 96] = h;
            keys[n] = fmaxf(keys[n], h);
        }
    }
    __syncthreads();

    // ---------------- head ----------------
    char*  HB   = (char*)Y;
    float* S30  = (float*)(HB + H_S30);
    float* c1wS = (float*)(HB + H_C1W);
    float* c2wS = (float*)(HB + H_C2W);
    float* L1   = (float*)(HB + H_L1);
    float* Q    = (float*)(HB + H_Q);
    float* Rr   = (float*)(HB + H_RR);
    float* Ff   = (float*)(HB + H_FF);

    if (t < 64) {
        // wave 0: top-30, jax.lax.top_k tie semantics (desc value, asc index)
        float kv[4]; int ki[4];
        #pragma unroll
        for (int r = 0; r < 4; ++r) { ki[r] = lane * 4 + r; kv[r] = keys[lane * 4 + r]; }
        for (int it = 0; it < 30; ++it) {
            float bv = kv[0]; int bi = ki[0];
            #pragma unroll
            for (int r = 1; r < 4; ++r)
                if (kv[r] > bv || (kv[r] == bv && ki[r] < bi)) { bv = kv[r]; bi = ki[r]; }
            #pragma unroll
            for (int off = 1; off <= 32; off <<= 1) {
                const float ov = __shfl_xor(bv, off, 64);
                const int   oi = __shfl_xor(bi, off, 64);
                if (ov > bv || (ov == bv && oi < bi)) { bv = ov; bi = oi; }
            }
            if (lane == 0) selI[it] = bi;
            if ((bi >> 2) == lane) kv[bi & 3] = -INFINITY;
        }
    } else {
        for (int i = t - 64; i < 1552; i += 960) c1wS[i] = c1w[i];
        for (int i = t - 64; i < 2560; i += 960) c2wS[i] = c2w[i];
    }
    __syncthreads();

    // bitonic-128 sort (ascending) of the 30 selected rows (from global F)
    for (int k = wv; k < 30; k += 16) {
        const float* fr = gFg + (size_t)selI[k] * 100;
        float v0 = fr[lane];
        float v1 = (lane < 33) ? fr[64 + lane] : INFINITY;
        for (int kk = 2; kk <= 128; kk <<= 1) {
            for (int jj = kk >> 1; jj > 0; jj >>= 1) {
                if (jj == 64) {
                    const float lo = fminf(v0, v1), hi = fmaxf(v0, v1);
                    v0 = lo; v1 = hi;
                } else {
                    const float p0 = __shfl_xor(v0, jj, 64);
                    const float p1 = __shfl_xor(v1, jj, 64);
                    const bool up   = ((lane & jj) == 0);
                    const bool asc0 = (kk == 128) ? true : ((lane & kk) == 0);
                    const bool asc1 = (kk == 128) ? true : (((64 + lane) & kk) == 0);
                    v0 = (up == asc0) ? fminf(v0, p0) : fmaxf(v0, p0);
                    v1 = (up == asc1) ? fminf(v1, p1) : fmaxf(v1, p1);
                }
            }
        }
        S30[k * 100 + lane] = v0;
        if (lane < 33) S30[k * 100 + 64 + lane] = v1;
    }
    __syncthreads();

    // conv1 (16 ch, kernel 97, stride 97) + relu
    if (t < 480) {
        const int k = t >> 4, c = t & 15;
        const float* row  = S30 + k * 100;
        const float* wrow = c1wS + c * 97;
        float acc = c1b[c];
        for (int d = 0; d < 97; ++d) acc = fmaf(row[d], wrow[d], acc);
        L1[k * 16 + c] = fmaxf(acc, 0.f);
    }
    __syncthreads();
    if (t < 240) {
        const int c = t / 15, tt = t % 15;
        Q[c * 15 + tt] = fmaxf(L1[(2 * tt) * 16 + c], L1[(2 * tt + 1) * 16 + c]);
    }
    __syncthreads();
    if (t < 352) {
        const int o = t / 11, tt = t % 11;
        const float* wo = c2wS + o * 80;
        float acc = c2b[o];
        #pragma unroll
        for (int c = 0; c < 16; ++c)
            #pragma unroll
            for (int jj = 0; jj < 5; ++jj)
                acc = fmaf(Q[c * 15 + tt + jj], wo[c * 5 + jj], acc);
        Rr[o * 11 + tt] = fmaxf(acc, 0.f);
    }
    __syncthreads();
    if (t < 128) {
        float acc = f1b[t];
        const float* wr = f1w + t * 352;
        for (int i = 0; i < 352; ++i) acc = fmaf(Rr[i], wr[i], acc);
        Ff[t] = fmaxf(acc, 0.f);
    }
    __syncthreads();
    if (t < 64) {
        float acc = Ff[lane] * f2w[lane] + Ff[lane + 64] * f2w[lane + 64];
        #pragma unroll
        for (int off = 1; off <= 32; off <<= 1) acc += __shfl_xor(acc, off, 64);
        if (lane == 0) out[g] = acc + f2b[0];
    }
}

extern "C" void kernel_launch(void* const* d_in, const int* in_sizes, int n_in,
                              void* d_out, int out_size, void* d_ws, size_t ws_size,
                              hipStream_t stream)
{
    const int*   feats    = (const int*)d_in[0];
    const int*   node_id  = (const int*)d_in[1];
    const int*   edge_id  = (const int*)d_in[2];
    const int*   src      = (const int*)d_in[3];
    const int*   dst      = (const int*)d_in[4];
    const float* ndata    = (const float*)d_in[5];
    const float* edata    = (const float*)d_in[6];
    const float* node_emb = (const float*)d_in[7];
    const float* W0 = (const float*)d_in[8];
    const float* b0 = (const float*)d_in[9];
    const float* W1 = (const float*)d_in[10];
    const float* b1 = (const float*)d_in[11];
    const float* W2 = (const float*)d_in[12];
    const float* b2 = (const float*)d_in[13];
    const float* W3 = (const float*)d_in[14];
    const float* b3 = (const float*)d_in[15];
    const float* c1w = (const float*)d_in[16];
    const float* c1b = (const float*)d_in[17];
    const float* c2w = (const float*)d_in[18];
    const float* c2b = (const float*)d_in[19];
    const float* f1w = (const float*)d_in[20];
    const float* f1b = (const float*)d_in[21];
    const float* f2w = (const float*)d_in[22];
    const float* f2b = (const float*)d_in[23];

    (void)hipFuncSetAttribute((const void*)dgcnn_fused,
                              hipFuncAttributeMaxDynamicSharedMemorySize, A_TOTAL);

    dgcnn_fused<<<NGRAPH, 1024, A_TOTAL, stream>>>(feats, node_id, edge_id, src, dst,
                                                   ndata, edata, node_emb,
                                                   W0, b0, W1, b1, W2, b2, W3, b3,
                                                   c1w, c1b, c2w, c2b,
                                                   f1w, f1b, f2w, f2b,
                                                   (float*)d_out);
}